// Round 1
// 484.423 us; speedup vs baseline: 1.0069x; 1.0069x over previous
//
#include <hip/hip_runtime.h>
#include <cstdint>
#include <cstddef>

#define E_EDGES 800000
#define N_NODES 50000
#define HDIM 128
#define HID 256
#define ME 64            // edges per block in edge kernel
#define NB 64            // nodes per block in node kernel
#define NTILES 196       // ceil(N_NODES/256) for the parallel scan

typedef __attribute__((ext_vector_type(8))) short short8;
typedef __attribute__((ext_vector_type(4))) float f32x4;

// fast silu: y * rcp(1 + exp(-y)); v_rcp_f32 ~1ulp, fine vs bf16 rounding
__device__ __forceinline__ float silu(float y) {
    return y * __builtin_amdgcn_rcpf(1.0f + __expf(-y));
}

// native RNE f32 -> bf16
__device__ __forceinline__ short f2bfn(float f) {
    __bf16 b = (__bf16)f;
    return __builtin_bit_cast(short, b);
}
__device__ __forceinline__ float bf2f(short s) {
    return __uint_as_float(((unsigned int)(unsigned short)s) << 16);
}

// ---------------- fused prep: h cvt + agg zero + hist + all weight cvts ----------------
// (cnt must be zeroed BEFORE this kernel: hist atomicAdds into it here)
// Wb1  [256][288]: k<257 = We1, k=257 = be1, else 0     (bias via MFMA tail)
// Wb2  [256][288]: k<256 = We2, k=256 = be2, else 0
// Wbn1 [256][416]: k<384 = Wn1, k=384 = bn1, else 0
// Wbn2 [128][288]: k<256 = Wn2, k=256 = bn2, else 0
#define PREP_H    6250                    // h fp32->bf16, 1600000 short4
#define PREP_AGG  (PREP_H + 12500)        // agg zero, 3200000 float4
#define PREP_HIST (PREP_AGG + 3125)       // hist over 800000 edges
#define PREP_WE1  (PREP_HIST + 288)
#define PREP_WE2  (PREP_WE1 + 288)
#define PREP_WN1  (PREP_WE2 + 416)
#define PREP_WN2  (PREP_WN1 + 144)
__global__ void prep_kernel(const float* __restrict__ h, short* __restrict__ hbf,
                            float* __restrict__ agg,
                            const int* __restrict__ row, int* __restrict__ cnt,
                            const float* __restrict__ We1, const float* __restrict__ be1,
                            short* __restrict__ Wb1,
                            const float* __restrict__ We2, const float* __restrict__ be2,
                            short* __restrict__ Wb2,
                            const float* __restrict__ Wn1, const float* __restrict__ bn1,
                            short* __restrict__ Wbn1,
                            const float* __restrict__ Wn2, const float* __restrict__ bn2,
                            short* __restrict__ Wbn2) {
    const int b = blockIdx.x, t = threadIdx.x;
    if (b < PREP_H) {
        int i = b * 256 + t;                      // quad index
        float4 v = ((const float4*)h)[i];
        short4 s;
        s.x = f2bfn(v.x); s.y = f2bfn(v.y); s.z = f2bfn(v.z); s.w = f2bfn(v.w);
        ((short4*)hbf)[i] = s;
    } else if (b < PREP_AGG) {
        int i = (b - PREP_H) * 256 + t;           // float4 index
        ((float4*)agg)[i] = make_float4(0.f, 0.f, 0.f, 0.f);
    } else if (b < PREP_HIST) {
        int e = (b - PREP_AGG) * 256 + t;
        if (e < E_EDGES) atomicAdd(&cnt[row[e]], 1);
    } else if (b < PREP_WE1) {
        int idx = (b - PREP_HIST) * 256 + t;      // 256*288
        int c = idx / 288, k = idx - c * 288;
        short v = 0;
        if (k < 257)       v = f2bfn(We1[c * 257 + k]);
        else if (k == 257) v = f2bfn(be1[c]);
        Wb1[idx] = v;
    } else if (b < PREP_WE2) {
        int idx = (b - PREP_WE1) * 256 + t;       // 256*288
        int c = idx / 288, k = idx - c * 288;
        short v = 0;
        if (k < 256)       v = f2bfn(We2[c * 256 + k]);
        else if (k == 256) v = f2bfn(be2[c]);
        Wb2[idx] = v;
    } else if (b < PREP_WN1) {
        int idx = (b - PREP_WE2) * 256 + t;       // 256*416
        int c = idx / 416, k = idx - c * 416;
        short v = 0;
        if (k < 384)       v = f2bfn(Wn1[c * 384 + k]);
        else if (k == 384) v = f2bfn(bn1[c]);
        Wbn1[idx] = v;
    } else {
        int idx = (b - PREP_WN1) * 256 + t;       // 128*288
        int c = idx / 288, k = idx - c * 288;
        short v = 0;
        if (k < 256)       v = f2bfn(Wn2[c * 256 + k]);
        else if (k == 256) v = f2bfn(bn2[c]);
        Wbn2[idx] = v;
    }
}

// ---------------- parallel CSR scan (3 small kernels) ----------------
__global__ void scanA_kernel(const int* __restrict__ cnt, int* __restrict__ incl,
                             int* __restrict__ tsum) {
    const int b = blockIdx.x, t = threadIdx.x;
    const int i = b * 256 + t;
    const int lane = t & 63, wv = t >> 6;
    int v = (i < N_NODES) ? cnt[i] : 0;
    int s = v;
#pragma unroll
    for (int off = 1; off < 64; off <<= 1) {
        int u = __shfl_up(s, off, 64);
        if (lane >= off) s += u;
    }
    __shared__ int wsum[4];
    if (lane == 63) wsum[wv] = s;
    __syncthreads();
    int pre = 0;
#pragma unroll
    for (int j = 0; j < 3; ++j) if (wv > j) pre += wsum[j];
    s += pre;
    if (i < N_NODES) incl[i] = s;
    if (t == 255) tsum[b] = s;
}

__global__ void scanB_kernel(const int* __restrict__ tsum, int* __restrict__ toff) {
    const int t = threadIdx.x;
    const int lane = t & 63, wv = t >> 6;
    int v = (t < NTILES) ? tsum[t] : 0;
    int s = v;
#pragma unroll
    for (int off = 1; off < 64; off <<= 1) {
        int u = __shfl_up(s, off, 64);
        if (lane >= off) s += u;
    }
    __shared__ int wsum[4];
    if (lane == 63) wsum[wv] = s;
    __syncthreads();
    int pre = 0;
#pragma unroll
    for (int j = 0; j < 3; ++j) if (wv > j) pre += wsum[j];
    s += pre;
    if (t < NTILES) toff[t] = s - v;   // exclusive
}

__global__ void scanC_kernel(const int* __restrict__ cnt, int* __restrict__ cursor,
                             const int* __restrict__ toff) {
    const int b = blockIdx.x, t = threadIdx.x;
    const int i = b * 256 + t;
    if (i < N_NODES) {
        cursor[i] = cursor[i] - cnt[i] + toff[b];   // incl -> excl + tile offset
    }
}

__global__ void fill_kernel(const int* __restrict__ row, int* __restrict__ cursor,
                            int* __restrict__ eidx) {
    int e = blockIdx.x * 256 + threadIdx.x;
    if (e < E_EDGES) {
        int pos = atomicAdd(&cursor[row[e]], 1);
        eidx[pos] = e;
    }
}

// ---------------- edge MLP (bf16 MFMA) + segmented scatter ----------------
// r17: layer-1 MFMA operand-swapped (acc[ct][et] = W^T-tile x X^T-tile) so each
// lane holds 4 CONSECUTIVE channels of one edge -> SiLU epilogue becomes 16
// packed short4 (b64) stores at the bank floor, replacing 128 scalar b16
// stores that were 4-8-way bank-conflicted (the 2.4e7 SQ_LDS_BANK_CONFLICT).
// Written M1 layout is bit-identical to before; layer 2 unchanged.
__global__ __launch_bounds__(256, 4) void edge_kernel(
    const short* __restrict__ hb, const float* __restrict__ coord,
    const int* __restrict__ row, const int* __restrict__ col,
    const int* __restrict__ eidx,
    const short* __restrict__ Wb1, const short* __restrict__ Wb2,
    float* __restrict__ agg)
{
    __shared__ __align__(16) short shPool[ME * 256 + ME * 32];
    __shared__ int sr[ME];
    short* shA = shPool;
    short* shT = shPool + ME * 256;

    const int t = threadIdx.x;
    const int nwg = E_EDGES / ME;
    const int qq = nwg >> 3, rr = nwg & 7;
    const int xcd = blockIdx.x & 7, bi = blockIdx.x >> 3;
    const int wg = (xcd < rr ? xcd * (qq + 1) : rr * (qq + 1) + (xcd - rr) * qq) + bi;
    const int e0 = wg * ME;

    // ---- stage gathered bf16 h rows (XOR chunk-swizzle) + radial/bias K-tail ----
    {
        const int e = t >> 2, q = t & 3;       // 4 threads/edge
        const int eo = eidx[e0 + e];
        const int src = (q < 2) ? row[eo] : col[eo];
        const short8* hp = (const short8*)(hb + (size_t)src * HDIM + (q & 1) * 64);
#pragma unroll
        for (int c = 0; c < 8; ++c) {
            short8 v = hp[c];
            int chunk = 8 * q + c;
            int sw = chunk ^ (e & 7);
            *(short8*)&shA[e * 256 + sw * 8] = v;
        }
        short8 z = {0, 0, 0, 0, 0, 0, 0, 0};
        if (q == 0) {
            float cx = coord[3 * eo + 0];
            float cy = coord[3 * eo + 1];
            float cz = coord[3 * eo + 2];
            z[0] = f2bfn(cx * cx + cy * cy + cz * cz);
            z[1] = (short)0x3F80;              // bf16 1.0 (bias multiplier)
            sr[e] = src;
        }
        *(short8*)&shT[e * 32 + ((q ^ (e & 3)) << 3)] = z;
    }
    __syncthreads();

    const int l = t & 63, w = t >> 6;
    const int l15 = l & 15, lq = l >> 4;

    f32x4 acc[4][4];
#pragma unroll
    for (int i = 0; i < 4; ++i)
#pragma unroll
        for (int j = 0; j < 4; ++j) acc[i][j] = (f32x4){0.f, 0.f, 0.f, 0.f};

    // ---- layer 1 (SWAPPED): K=256 (+32 tail) MFMA; acc[ct][et] rows=channels ----
#pragma unroll
    for (int ks = 0; ks < 8; ++ks) {
        short8 a[4], b[4];
#pragma unroll
        for (int et = 0; et < 4; ++et) {
            int r = et * 16 + l15;
            int chunk = ks * 4 + lq;
            a[et] = *(const short8*)&shA[r * 256 + ((chunk ^ (r & 7)) << 3)];
        }
#pragma unroll
        for (int ct = 0; ct < 4; ++ct) {
            int cc = w * 64 + ct * 16 + l15;
            b[ct] = *(const short8*)&Wb1[cc * 288 + ks * 32 + lq * 8];
        }
#pragma unroll
        for (int et = 0; et < 4; ++et)
#pragma unroll
            for (int ct = 0; ct < 4; ++ct)
                acc[ct][et] = __builtin_amdgcn_mfma_f32_16x16x32_bf16(
                    b[ct], a[et], acc[ct][et], 0, 0, 0);
    }
    {   // tail K-step (k = 256..287): radial + bias (swapped like main loop)
        short8 a[4], b[4];
#pragma unroll
        for (int et = 0; et < 4; ++et) {
            int r = et * 16 + l15;
            a[et] = *(const short8*)&shT[r * 32 + ((lq ^ (r & 3)) << 3)];
        }
#pragma unroll
        for (int ct = 0; ct < 4; ++ct) {
            int cc = w * 64 + ct * 16 + l15;
            b[ct] = *(const short8*)&Wb1[cc * 288 + 256 + lq * 8];
        }
#pragma unroll
        for (int et = 0; et < 4; ++et)
#pragma unroll
            for (int ct = 0; ct < 4; ++ct)
                acc[ct][et] = __builtin_amdgcn_mfma_f32_16x16x32_bf16(
                    b[ct], a[et], acc[ct][et], 0, 0, 0);
    }
    __syncthreads();

    // ---- SiLU -> M1 (bf16, swizzled) via packed short4 (bank-floor b64 stores);
    //      rewrite tail to {1.0,0..} ----
    {
        if (t < ME) {
            *(unsigned int*)&shT[t * 32 + ((t & 3) << 3)] = 0x00003F80u;
        }
#pragma unroll
        for (int ct = 0; ct < 4; ++ct) {
#pragma unroll
            for (int et = 0; et < 4; ++et) {
                int e = et * 16 + l15;                 // edge (acc col)
                int chb = w * 64 + ct * 16 + lq * 4;   // first of 4 consecutive channels
                short4 s;
                s.x = f2bfn(silu(acc[ct][et][0]));
                s.y = f2bfn(silu(acc[ct][et][1]));
                s.z = f2bfn(silu(acc[ct][et][2]));
                s.w = f2bfn(silu(acc[ct][et][3]));
                int chunk = chb >> 3;                  // chb ≡ 0 (mod 4): stays in one chunk
                *(short4*)&shA[e * 256 + ((chunk ^ (e & 7)) << 3) + (chb & 7)] = s;
            }
        }
    }
    __syncthreads();

    // ---- layer 2: K=256 (+32 tail: bias) MFMA (unswapped; epilogue already at floor) ----
#pragma unroll
    for (int i = 0; i < 4; ++i)
#pragma unroll
        for (int j = 0; j < 4; ++j) acc[i][j] = (f32x4){0.f, 0.f, 0.f, 0.f};
#pragma unroll
    for (int ks = 0; ks < 8; ++ks) {
        short8 a[4], b[4];
#pragma unroll
        for (int et = 0; et < 4; ++et) {
            int r = et * 16 + l15;
            int chunk = ks * 4 + lq;
            a[et] = *(const short8*)&shA[r * 256 + ((chunk ^ (r & 7)) << 3)];
        }
#pragma unroll
        for (int ct = 0; ct < 4; ++ct) {
            int cc = w * 64 + ct * 16 + l15;
            b[ct] = *(const short8*)&Wb2[cc * 288 + ks * 32 + lq * 8];
        }
#pragma unroll
        for (int et = 0; et < 4; ++et)
#pragma unroll
            for (int ct = 0; ct < 4; ++ct)
                acc[et][ct] = __builtin_amdgcn_mfma_f32_16x16x32_bf16(
                    a[et], b[ct], acc[et][ct], 0, 0, 0);
    }
    {   // tail K-step: bias (A = {1.0,0...})
        short8 a[4], b[4];
#pragma unroll
        for (int et = 0; et < 4; ++et) {
            int r = et * 16 + l15;
            a[et] = *(const short8*)&shT[r * 32 + ((lq ^ (r & 3)) << 3)];
        }
#pragma unroll
        for (int ct = 0; ct < 4; ++ct) {
            int cc = w * 64 + ct * 16 + l15;
            b[ct] = *(const short8*)&Wb2[cc * 288 + 256 + lq * 8];
        }
#pragma unroll
        for (int et = 0; et < 4; ++et)
#pragma unroll
            for (int ct = 0; ct < 4; ++ct)
                acc[et][ct] = __builtin_amdgcn_mfma_f32_16x16x32_bf16(
                    a[et], b[ct], acc[et][ct], 0, 0, 0);
    }
    __syncthreads();

    // ---- SiLU -> C2 TRANSPOSED [n][e], stride 68, packed short4 writes ----
    {
#pragma unroll
        for (int ct = 0; ct < 4; ++ct) {
#pragma unroll
            for (int et = 0; et < 4; ++et) {
                int kc = w * 64 + ct * 16 + l15;
                int er0 = et * 16 + lq * 4;
                short4 s;
                s.x = f2bfn(silu(acc[et][ct][0]));
                s.y = f2bfn(silu(acc[et][ct][1]));
                s.z = f2bfn(silu(acc[et][ct][2]));
                s.w = f2bfn(silu(acc[et][ct][3]));
                *(short4*)&shPool[kc * 68 + er0] = s;
            }
        }
    }
    __syncthreads();

    // ---- segmented reduction (vectorized short4 reads); coalesced atomics ----
    // segment ids are wave-uniform -> readfirstlane pins the compare/branch to SALU
    {
        const int cc = t;
        const short* myrow = &shPool[cc * 68];
        float accum = 0.f;
        int cur = __builtin_amdgcn_readfirstlane(sr[0]);
        for (int eb = 0; eb < ME; eb += 4) {
            short4 v4 = *(const short4*)&myrow[eb];
            short vj[4] = {v4.x, v4.y, v4.z, v4.w};
#pragma unroll
            for (int j = 0; j < 4; ++j) {
                float v = bf2f(vj[j]);
                int r = __builtin_amdgcn_readfirstlane(sr[eb + j]);
                if (r != cur) {
                    atomicAdd(&agg[(size_t)cur * HID + cc], accum);
                    accum = v;
                    cur = r;
                } else {
                    accum += v;
                }
            }
        }
        atomicAdd(&agg[(size_t)cur * HID + cc], accum);
    }
}

// ---------------- node MLP (bf16 MFMA), 64 nodes/block, biases via MFMA tails ----------------
// B-fragment loads amortized over 64 output rows (2x vs the 32-node version);
// LDS 52 KB -> 3 blocks/CU (throughput-bound kernel family; occupancy secondary).
__global__ __launch_bounds__(256, 3) void node_kernel(
    const short* __restrict__ hbf, const float* __restrict__ agg,
    const short* __restrict__ Wbn1, const short* __restrict__ Wbn2,
    float* __restrict__ out)
{
    __shared__ __align__(16) short pool[NB * 384];  // 48 KB: shH + shAg; shM overlays
    __shared__ __align__(16) short shTn[NB * 32];   // 4 KB bias K-tail {1,0,..}
    short* shH  = pool;                 // [64][128] bf16 (swizzled)
    short* shAg = pool + NB * 128;      // [64][256] bf16 (swizzled)
    short* shM  = pool;                 // [64][256] bf16 (swizzled) — overlays

    const int t  = threadIdx.x;
    const int n0 = blockIdx.x * NB;

    // ---- stage h (bf16 copy), agg (f32 -> bf16), bias tail; 4 threads/node ----
    {
        const int n = t >> 2, q = t & 3;
        int gn = n0 + n;
        if (gn >= N_NODES) gn = N_NODES - 1;   // clamp loads; stores guarded later
        const short8* hp = (const short8*)(hbf + (size_t)gn * HDIM + q * 32);
#pragma unroll
        for (int c = 0; c < 4; ++c) {
            short8 v = hp[c];
            int chunk = q * 4 + c;             // 0..15
            int sw = chunk ^ (n & 7);
            *(short8*)&shH[n * 128 + sw * 8] = v;
        }
        const float4* ap = (const float4*)(agg + (size_t)gn * HID + q * 64);
#pragma unroll
        for (int i = 0; i < 8; ++i) {
            float4 u0 = ap[2 * i], u1 = ap[2 * i + 1];
            short8 s;
            s[0] = f2bfn(u0.x); s[1] = f2bfn(u0.y); s[2] = f2bfn(u0.z); s[3] = f2bfn(u0.w);
            s[4] = f2bfn(u1.x); s[5] = f2bfn(u1.y); s[6] = f2bfn(u1.z); s[7] = f2bfn(u1.w);
            int chunk = q * 8 + i;             // 0..31
            int sw2 = chunk ^ (n & 7);
            *(short8*)&shAg[n * 256 + sw2 * 8] = s;
        }
        short8 z = {0, 0, 0, 0, 0, 0, 0, 0};
        if (q == 0) z[0] = (short)0x3F80;      // bf16 1.0
        *(short8*)&shTn[n * 32 + ((q ^ (n & 3)) << 3)] = z;
    }
    __syncthreads();

    const int l = t & 63, w = t >> 6;
    const int l15 = l & 15, lq = l >> 4;

    // ---- layer 1: K=384 (+32 bias tail), 256 cols, 64 rows ----
    f32x4 acc[4][4];
#pragma unroll
    for (int i = 0; i < 4; ++i)
#pragma unroll
        for (int j = 0; j < 4; ++j) acc[i][j] = (f32x4){0.f, 0.f, 0.f, 0.f};
#pragma unroll
    for (int ks = 0; ks < 12; ++ks) {
        short8 a[4], b[4];
#pragma unroll
        for (int et = 0; et < 4; ++et) {
            int r = et * 16 + l15;
            if (ks < 4) {
                int chunk = ks * 4 + lq;
                a[et] = *(const short8*)&shH[r * 128 + ((chunk ^ (r & 7)) << 3)];
            } else {
                int chunk = (ks - 4) * 4 + lq;
                a[et] = *(const short8*)&shAg[r * 256 + ((chunk ^ (r & 7)) << 3)];
            }
        }
#pragma unroll
        for (int ct = 0; ct < 4; ++ct) {
            int cc = w * 64 + ct * 16 + l15;
            b[ct] = *(const short8*)&Wbn1[cc * 416 + ks * 32 + lq * 8];
        }
#pragma unroll
        for (int et = 0; et < 4; ++et)
#pragma unroll
            for (int ct = 0; ct < 4; ++ct)
                acc[et][ct] = __builtin_amdgcn_mfma_f32_16x16x32_bf16(
                    a[et], b[ct], acc[et][ct], 0, 0, 0);
    }
    {   // bias tail (k = 384..415)
        short8 a[4], b[4];
#pragma unroll
        for (int et = 0; et < 4; ++et) {
            int r = et * 16 + l15;
            a[et] = *(const short8*)&shTn[r * 32 + ((lq ^ (r & 3)) << 3)];
        }
#pragma unroll
        for (int ct = 0; ct < 4; ++ct) {
            int cc = w * 64 + ct * 16 + l15;
            b[ct] = *(const short8*)&Wbn1[cc * 416 + 384 + lq * 8];
        }
#pragma unroll
        for (int et = 0; et < 4; ++et)
#pragma unroll
            for (int ct = 0; ct < 4; ++ct)
                acc[et][ct] = __builtin_amdgcn_mfma_f32_16x16x32_bf16(
                    a[et], b[ct], acc[et][ct], 0, 0, 0);
    }
    __syncthreads();   // done reading shH/shAg before shM overlay write

    // ---- SiLU -> M (bf16, swizzled; no bias add) ----
    {
#pragma unroll
        for (int et = 0; et < 4; ++et) {
#pragma unroll
            for (int rp = 0; rp < 2; ++rp) {
                int er0 = et * 16 + lq * 4 + rp * 2;
#pragma unroll
                for (int ct = 0; ct < 4; ++ct) {
                    int kc = w * 64 + ct * 16 + l15;
                    float y0 = silu(acc[et][ct][rp * 2]);
                    float y1 = silu(acc[et][ct][rp * 2 + 1]);
                    int khi = kc >> 3, klo = kc & 7;
                    shM[er0 * 256 + ((khi ^ (er0 & 7)) << 3) + klo] = f2bfn(y0);
                    shM[(er0 + 1) * 256 + ((khi ^ ((er0 + 1) & 7)) << 3) + klo] = f2bfn(y1);
                }
            }
        }
    }
    __syncthreads();

    // ---- layer 2: K=256 (+32 bias tail), 128 cols (32 per wave), 64 rows ----
    f32x4 acc2[4][2];
#pragma unroll
    for (int i = 0; i < 4; ++i)
#pragma unroll
        for (int j = 0; j < 2; ++j) acc2[i][j] = (f32x4){0.f, 0.f, 0.f, 0.f};
#pragma unroll
    for (int ks = 0; ks < 8; ++ks) {
        short8 a[4], b2[2];
#pragma unroll
        for (int et = 0; et < 4; ++et) {
            int r = et * 16 + l15;
            int chunk = ks * 4 + lq;
            a[et] = *(const short8*)&shM[r * 256 + ((chunk ^ (r & 7)) << 3)];
        }
#pragma unroll
        for (int ct = 0; ct < 2; ++ct) {
            int cc = w * 32 + ct * 16 + l15;
            b2[ct] = *(const short8*)&Wbn2[cc * 288 + ks * 32 + lq * 8];
        }
#pragma unroll
        for (int et = 0; et < 4; ++et)
#pragma unroll
            for (int ct = 0; ct < 2; ++ct)
                acc2[et][ct] = __builtin_amdgcn_mfma_f32_16x16x32_bf16(
                    a[et], b2[ct], acc2[et][ct], 0, 0, 0);
    }
    {   // bias tail (k = 256..287); shTn not overlaid
        short8 a[4], b2[2];
#pragma unroll
        for (int et = 0; et < 4; ++et) {
            int r = et * 16 + l15;
            a[et] = *(const short8*)&shTn[r * 32 + ((lq ^ (r & 3)) << 3)];
        }
#pragma unroll
        for (int ct = 0; ct < 2; ++ct) {
            int cc = w * 32 + ct * 16 + l15;
            b2[ct] = *(const short8*)&Wbn2[cc * 288 + 256 + lq * 8];
        }
#pragma unroll
        for (int et = 0; et < 4; ++et)
#pragma unroll
            for (int ct = 0; ct < 2; ++ct)
                acc2[et][ct] = __builtin_amdgcn_mfma_f32_16x16x32_bf16(
                    a[et], b2[ct], acc2[et][ct], 0, 0, 0);
    }

    // ---- store (bias already in acc2) ----
#pragma unroll
    for (int et = 0; et < 4; ++et) {
#pragma unroll
        for (int ct = 0; ct < 2; ++ct) {
            int cc = w * 32 + ct * 16 + l15;
#pragma unroll
            for (int r4 = 0; r4 < 4; ++r4) {
                int gn = n0 + et * 16 + lq * 4 + r4;
                if (gn < N_NODES)
                    out[(size_t)gn * HDIM + cc] = acc2[et][ct][r4];
            }
        }
    }
}

extern "C" void kernel_launch(void* const* d_in, const int* in_sizes, int n_in,
                              void* d_out, int out_size, void* d_ws, size_t ws_size,
                              hipStream_t stream) {
    const float* h   = (const float*)d_in[0];
    const float* cd  = (const float*)d_in[1];
    const int*   row = (const int*)d_in[2];
    const int*   col = (const int*)d_in[3];
    const float* We1 = (const float*)d_in[4];
    const float* be1 = (const float*)d_in[5];
    const float* We2 = (const float*)d_in[6];
    const float* be2 = (const float*)d_in[7];
    const float* Wn1 = (const float*)d_in[8];
    const float* bn1 = (const float*)d_in[9];
    const float* Wn2 = (const float*)d_in[10];
    const float* bn2 = (const float*)d_in[11];
    float* out = (float*)d_out;

    // ---- workspace layout ----
    short* Wb1  = (short*)d_ws;                       // 256*288
    short* Wb2  = Wb1 + 256 * 288;                    // 256*288
    short* Wbn1 = Wb2 + 256 * 288;                    // 256*416
    short* Wbn2 = Wbn1 + 256 * 416;                   // 128*288
    short* hbf  = Wbn2 + 128 * 288;                   // 50000*128
    float* agg  = (float*)(hbf + (size_t)N_NODES * HDIM);  // 50000*256 f32
    int*   cnt    = (int*)(agg + (size_t)N_NODES * HID);   // 50000
    int*   cursor = cnt + N_NODES;                    // 50000 (also scan scratch)
    int*   eidx   = cursor + N_NODES;                 // 800000
    int*   tsum   = eidx + E_EDGES;                   // 256
    int*   toff   = tsum + 256;                       // 256

    // cnt must be zero before prep's fused hist
    hipMemsetAsync(cnt, 0, N_NODES * sizeof(int), stream);

    // fused prep: h cvt + agg zero + hist + weight cvts (one launch)
    prep_kernel<<<PREP_WN2, 256, 0, stream>>>(h, hbf, agg, row, cnt,
                                              We1, be1, Wb1, We2, be2, Wb2,
                                              Wn1, bn1, Wbn1, Wn2, bn2, Wbn2);

    // parallel CSR scan -> cursor
    scanA_kernel<<<NTILES, 256, 0, stream>>>(cnt, cursor, tsum);
    scanB_kernel<<<1, 256, 0, stream>>>(tsum, toff);
    scanC_kernel<<<NTILES, 256, 0, stream>>>(cnt, cursor, toff);
    fill_kernel<<<(E_EDGES + 255) / 256, 256, 0, stream>>>(row, cursor, eidx);

    // main
    edge_kernel<<<E_EDGES / ME, 256, 0, stream>>>(hbf, cd, row, col, eidx,
                                                  Wb1, Wb2, agg);
    node_kernel<<<(N_NODES + NB - 1) / NB, 256, 0, stream>>>(hbf, agg, Wbn1, Wbn2, out);
}

// Round 2
// 476.264 us; speedup vs baseline: 1.0241x; 1.0171x over previous
//
#include <hip/hip_runtime.h>
#include <cstdint>
#include <cstddef>

#define E_EDGES 800000
#define N_NODES 50000
#define HDIM 128
#define HID 256
#define ME 64            // edges per block in edge kernel
#define NB 64            // nodes per block in node kernel
#define NTILES 196       // ceil(N_NODES/256) for the parallel scan

typedef __attribute__((ext_vector_type(8))) short short8;
typedef __attribute__((ext_vector_type(4))) float f32x4;

// fast silu: y * rcp(1 + exp(-y)); v_rcp_f32 ~1ulp, fine vs bf16 rounding
__device__ __forceinline__ float silu(float y) {
    return y * __builtin_amdgcn_rcpf(1.0f + __expf(-y));
}

// native RNE f32 -> bf16
__device__ __forceinline__ short f2bfn(float f) {
    __bf16 b = (__bf16)f;
    return __builtin_bit_cast(short, b);
}
__device__ __forceinline__ float bf2f(short s) {
    return __uint_as_float(((unsigned int)(unsigned short)s) << 16);
}

// ---------------- fused prep: h cvt + agg zero + hist + all weight cvts ----------------
// (cnt must be zeroed BEFORE this kernel: hist atomicAdds into it here)
// Wb1  [256][288]: k<257 = We1, k=257 = be1, else 0     (bias via MFMA tail)
// Wb2  [256][288]: k<256 = We2, k=256 = be2, else 0
// Wbn1 [256][416]: k<384 = Wn1, k=384 = bn1, else 0
// Wbn2 [128][288]: k<256 = Wn2, k=256 = bn2, else 0
#define PREP_H    6250                    // h fp32->bf16, 1600000 short4
#define PREP_AGG  (PREP_H + 12500)        // agg zero, 3200000 float4
#define PREP_HIST (PREP_AGG + 3125)       // hist over 800000 edges
#define PREP_WE1  (PREP_HIST + 288)
#define PREP_WE2  (PREP_WE1 + 288)
#define PREP_WN1  (PREP_WE2 + 416)
#define PREP_WN2  (PREP_WN1 + 144)
__global__ void prep_kernel(const float* __restrict__ h, short* __restrict__ hbf,
                            float* __restrict__ agg,
                            const int* __restrict__ row, int* __restrict__ cnt,
                            const float* __restrict__ We1, const float* __restrict__ be1,
                            short* __restrict__ Wb1,
                            const float* __restrict__ We2, const float* __restrict__ be2,
                            short* __restrict__ Wb2,
                            const float* __restrict__ Wn1, const float* __restrict__ bn1,
                            short* __restrict__ Wbn1,
                            const float* __restrict__ Wn2, const float* __restrict__ bn2,
                            short* __restrict__ Wbn2) {
    const int b = blockIdx.x, t = threadIdx.x;
    if (b < PREP_H) {
        int i = b * 256 + t;                      // quad index
        float4 v = ((const float4*)h)[i];
        short4 s;
        s.x = f2bfn(v.x); s.y = f2bfn(v.y); s.z = f2bfn(v.z); s.w = f2bfn(v.w);
        ((short4*)hbf)[i] = s;
    } else if (b < PREP_AGG) {
        int i = (b - PREP_H) * 256 + t;           // float4 index
        ((float4*)agg)[i] = make_float4(0.f, 0.f, 0.f, 0.f);
    } else if (b < PREP_HIST) {
        int e = (b - PREP_AGG) * 256 + t;
        if (e < E_EDGES) atomicAdd(&cnt[row[e]], 1);
    } else if (b < PREP_WE1) {
        int idx = (b - PREP_HIST) * 256 + t;      // 256*288
        int c = idx / 288, k = idx - c * 288;
        short v = 0;
        if (k < 257)       v = f2bfn(We1[c * 257 + k]);
        else if (k == 257) v = f2bfn(be1[c]);
        Wb1[idx] = v;
    } else if (b < PREP_WE2) {
        int idx = (b - PREP_WE1) * 256 + t;       // 256*288
        int c = idx / 288, k = idx - c * 288;
        short v = 0;
        if (k < 256)       v = f2bfn(We2[c * 256 + k]);
        else if (k == 256) v = f2bfn(be2[c]);
        Wb2[idx] = v;
    } else if (b < PREP_WN1) {
        int idx = (b - PREP_WE2) * 256 + t;       // 256*416
        int c = idx / 416, k = idx - c * 416;
        short v = 0;
        if (k < 384)       v = f2bfn(Wn1[c * 384 + k]);
        else if (k == 384) v = f2bfn(bn1[c]);
        Wbn1[idx] = v;
    } else {
        int idx = (b - PREP_WN1) * 256 + t;       // 128*288
        int c = idx / 288, k = idx - c * 288;
        short v = 0;
        if (k < 256)       v = f2bfn(Wn2[c * 256 + k]);
        else if (k == 256) v = f2bfn(bn2[c]);
        Wbn2[idx] = v;
    }
}

// ---------------- parallel CSR scan (3 small kernels) ----------------
__global__ void scanA_kernel(const int* __restrict__ cnt, int* __restrict__ incl,
                             int* __restrict__ tsum) {
    const int b = blockIdx.x, t = threadIdx.x;
    const int i = b * 256 + t;
    const int lane = t & 63, wv = t >> 6;
    int v = (i < N_NODES) ? cnt[i] : 0;
    int s = v;
#pragma unroll
    for (int off = 1; off < 64; off <<= 1) {
        int u = __shfl_up(s, off, 64);
        if (lane >= off) s += u;
    }
    __shared__ int wsum[4];
    if (lane == 63) wsum[wv] = s;
    __syncthreads();
    int pre = 0;
#pragma unroll
    for (int j = 0; j < 3; ++j) if (wv > j) pre += wsum[j];
    s += pre;
    if (i < N_NODES) incl[i] = s;
    if (t == 255) tsum[b] = s;
}

__global__ void scanB_kernel(const int* __restrict__ tsum, int* __restrict__ toff) {
    const int t = threadIdx.x;
    const int lane = t & 63, wv = t >> 6;
    int v = (t < NTILES) ? tsum[t] : 0;
    int s = v;
#pragma unroll
    for (int off = 1; off < 64; off <<= 1) {
        int u = __shfl_up(s, off, 64);
        if (lane >= off) s += u;
    }
    __shared__ int wsum[4];
    if (lane == 63) wsum[wv] = s;
    __syncthreads();
    int pre = 0;
#pragma unroll
    for (int j = 0; j < 3; ++j) if (wv > j) pre += wsum[j];
    s += pre;
    if (t < NTILES) toff[t] = s - v;   // exclusive
}

__global__ void scanC_kernel(const int* __restrict__ cnt, int* __restrict__ cursor,
                             const int* __restrict__ toff) {
    const int b = blockIdx.x, t = threadIdx.x;
    const int i = b * 256 + t;
    if (i < N_NODES) {
        cursor[i] = cursor[i] - cnt[i] + toff[b];   // incl -> excl + tile offset
    }
}

__global__ void fill_kernel(const int* __restrict__ row, int* __restrict__ cursor,
                            int* __restrict__ eidx) {
    int e = blockIdx.x * 256 + threadIdx.x;
    if (e < E_EDGES) {
        int pos = atomicAdd(&cursor[row[e]], 1);
        eidx[pos] = e;
    }
}

// ---------------- edge MLP (bf16 MFMA) + segmented scatter ----------------
// r18: explicit 2-deep software pipeline in both GEMM loops. r17's null result
// + VGPR_Count=64 showed the kernel was latency-bound: launch_bounds(256,4)
// capped unified regs at 128 (64 acc + 64 working set), so each K-step was
// issue-loads -> waitcnt -> MFMA, fully serialized. Now: launch_bounds(256,2)
// (reg cap 256) + prefetch K-step k+1's A (LDS) and B (global weight) fragments
// into a second register set while step k's 16 MFMAs run. Occupancy drops to
// ~8 waves/CU; ILP replaces TLP. setprio(1) around MFMA clusters (T5).
__global__ __launch_bounds__(256, 2) void edge_kernel(
    const short* __restrict__ hb, const float* __restrict__ coord,
    const int* __restrict__ row, const int* __restrict__ col,
    const int* __restrict__ eidx,
    const short* __restrict__ Wb1, const short* __restrict__ Wb2,
    float* __restrict__ agg)
{
    __shared__ __align__(16) short shPool[ME * 256 + ME * 32];
    __shared__ int sr[ME];
    short* shA = shPool;
    short* shT = shPool + ME * 256;

    const int t = threadIdx.x;
    const int nwg = E_EDGES / ME;
    const int qq = nwg >> 3, rr = nwg & 7;
    const int xcd = blockIdx.x & 7, bi = blockIdx.x >> 3;
    const int wg = (xcd < rr ? xcd * (qq + 1) : rr * (qq + 1) + (xcd - rr) * qq) + bi;
    const int e0 = wg * ME;

    // ---- stage gathered bf16 h rows (XOR chunk-swizzle) + radial/bias K-tail ----
    {
        const int e = t >> 2, q = t & 3;       // 4 threads/edge
        const int eo = eidx[e0 + e];
        const int src = (q < 2) ? row[eo] : col[eo];
        const short8* hp = (const short8*)(hb + (size_t)src * HDIM + (q & 1) * 64);
#pragma unroll
        for (int c = 0; c < 8; ++c) {
            short8 v = hp[c];
            int chunk = 8 * q + c;
            int sw = chunk ^ (e & 7);
            *(short8*)&shA[e * 256 + sw * 8] = v;
        }
        short8 z = {0, 0, 0, 0, 0, 0, 0, 0};
        if (q == 0) {
            float cx = coord[3 * eo + 0];
            float cy = coord[3 * eo + 1];
            float cz = coord[3 * eo + 2];
            z[0] = f2bfn(cx * cx + cy * cy + cz * cz);
            z[1] = (short)0x3F80;              // bf16 1.0 (bias multiplier)
            sr[e] = src;
        }
        *(short8*)&shT[e * 32 + ((q ^ (e & 3)) << 3)] = z;
    }
    __syncthreads();

    const int l = t & 63, w = t >> 6;
    const int l15 = l & 15, lq = l >> 4;

    f32x4 acc[4][4];
#pragma unroll
    for (int i = 0; i < 4; ++i)
#pragma unroll
        for (int j = 0; j < 4; ++j) acc[i][j] = (f32x4){0.f, 0.f, 0.f, 0.f};

    // ---- layer 1 (SWAPPED, pipelined): K=256 (+32 tail); acc[ct][et] rows=channels ----
    {
        short8 aC[4], bC[4], aN[4], bN[4];
#pragma unroll
        for (int et = 0; et < 4; ++et) {
            int r = et * 16 + l15;
            aC[et] = *(const short8*)&shA[r * 256 + ((lq ^ (r & 7)) << 3)];   // ks=0
        }
#pragma unroll
        for (int ct = 0; ct < 4; ++ct) {
            int cc = w * 64 + ct * 16 + l15;
            bC[ct] = *(const short8*)&Wb1[cc * 288 + lq * 8];                 // ks=0
        }
#pragma unroll
        for (int ks = 0; ks < 9; ++ks) {
            if (ks < 8) {   // prefetch ks+1 (ks+1==8 is the radial/bias tail)
                if (ks < 7) {
#pragma unroll
                    for (int et = 0; et < 4; ++et) {
                        int r = et * 16 + l15;
                        int chunk = (ks + 1) * 4 + lq;
                        aN[et] = *(const short8*)&shA[r * 256 + ((chunk ^ (r & 7)) << 3)];
                    }
                } else {
#pragma unroll
                    for (int et = 0; et < 4; ++et) {
                        int r = et * 16 + l15;
                        aN[et] = *(const short8*)&shT[r * 32 + ((lq ^ (r & 3)) << 3)];
                    }
                }
#pragma unroll
                for (int ct = 0; ct < 4; ++ct) {
                    int cc = w * 64 + ct * 16 + l15;
                    bN[ct] = *(const short8*)&Wb1[cc * 288 + (ks + 1) * 32 + lq * 8];
                }
            }
            __builtin_amdgcn_s_setprio(1);
#pragma unroll
            for (int et = 0; et < 4; ++et)
#pragma unroll
                for (int ct = 0; ct < 4; ++ct)
                    acc[ct][et] = __builtin_amdgcn_mfma_f32_16x16x32_bf16(
                        bC[ct], aC[et], acc[ct][et], 0, 0, 0);
            __builtin_amdgcn_s_setprio(0);
            if (ks < 8) {
#pragma unroll
                for (int i = 0; i < 4; ++i) { aC[i] = aN[i]; bC[i] = bN[i]; }
            }
        }
    }
    __syncthreads();

    // ---- SiLU -> M1 (bf16, swizzled) via packed short4 (bank-floor b64 stores);
    //      rewrite tail to {1.0,0..} ----
    {
        if (t < ME) {
            *(unsigned int*)&shT[t * 32 + ((t & 3) << 3)] = 0x00003F80u;
        }
#pragma unroll
        for (int ct = 0; ct < 4; ++ct) {
#pragma unroll
            for (int et = 0; et < 4; ++et) {
                int e = et * 16 + l15;                 // edge (acc col)
                int chb = w * 64 + ct * 16 + lq * 4;   // first of 4 consecutive channels
                short4 s;
                s.x = f2bfn(silu(acc[ct][et][0]));
                s.y = f2bfn(silu(acc[ct][et][1]));
                s.z = f2bfn(silu(acc[ct][et][2]));
                s.w = f2bfn(silu(acc[ct][et][3]));
                int chunk = chb >> 3;                  // chb ≡ 0 (mod 4): stays in one chunk
                *(short4*)&shA[e * 256 + ((chunk ^ (e & 7)) << 3) + (chb & 7)] = s;
            }
        }
    }
    __syncthreads();

    // ---- layer 2 (pipelined): K=256 (+32 tail: bias) ----
#pragma unroll
    for (int i = 0; i < 4; ++i)
#pragma unroll
        for (int j = 0; j < 4; ++j) acc[i][j] = (f32x4){0.f, 0.f, 0.f, 0.f};
    {
        short8 aC[4], bC[4], aN[4], bN[4];
#pragma unroll
        for (int et = 0; et < 4; ++et) {
            int r = et * 16 + l15;
            aC[et] = *(const short8*)&shA[r * 256 + ((lq ^ (r & 7)) << 3)];   // ks=0
        }
#pragma unroll
        for (int ct = 0; ct < 4; ++ct) {
            int cc = w * 64 + ct * 16 + l15;
            bC[ct] = *(const short8*)&Wb2[cc * 288 + lq * 8];                 // ks=0
        }
#pragma unroll
        for (int ks = 0; ks < 9; ++ks) {
            if (ks < 8) {   // prefetch ks+1 (ks+1==8 is the bias tail: A={1,0,..})
                if (ks < 7) {
#pragma unroll
                    for (int et = 0; et < 4; ++et) {
                        int r = et * 16 + l15;
                        int chunk = (ks + 1) * 4 + lq;
                        aN[et] = *(const short8*)&shA[r * 256 + ((chunk ^ (r & 7)) << 3)];
                    }
                } else {
#pragma unroll
                    for (int et = 0; et < 4; ++et) {
                        int r = et * 16 + l15;
                        aN[et] = *(const short8*)&shT[r * 32 + ((lq ^ (r & 3)) << 3)];
                    }
                }
#pragma unroll
                for (int ct = 0; ct < 4; ++ct) {
                    int cc = w * 64 + ct * 16 + l15;
                    bN[ct] = *(const short8*)&Wb2[cc * 288 + (ks + 1) * 32 + lq * 8];
                }
            }
            __builtin_amdgcn_s_setprio(1);
#pragma unroll
            for (int et = 0; et < 4; ++et)
#pragma unroll
                for (int ct = 0; ct < 4; ++ct)
                    acc[et][ct] = __builtin_amdgcn_mfma_f32_16x16x32_bf16(
                        aC[et], bC[ct], acc[et][ct], 0, 0, 0);
            __builtin_amdgcn_s_setprio(0);
            if (ks < 8) {
#pragma unroll
                for (int i = 0; i < 4; ++i) { aC[i] = aN[i]; bC[i] = bN[i]; }
            }
        }
    }
    __syncthreads();

    // ---- SiLU -> C2 TRANSPOSED [n][e], stride 68, packed short4 writes ----
    {
#pragma unroll
        for (int ct = 0; ct < 4; ++ct) {
#pragma unroll
            for (int et = 0; et < 4; ++et) {
                int kc = w * 64 + ct * 16 + l15;
                int er0 = et * 16 + lq * 4;
                short4 s;
                s.x = f2bfn(silu(acc[et][ct][0]));
                s.y = f2bfn(silu(acc[et][ct][1]));
                s.z = f2bfn(silu(acc[et][ct][2]));
                s.w = f2bfn(silu(acc[et][ct][3]));
                *(short4*)&shPool[kc * 68 + er0] = s;
            }
        }
    }
    __syncthreads();

    // ---- segmented reduction (vectorized short4 reads); coalesced atomics ----
    // segment ids are wave-uniform -> readfirstlane pins the compare/branch to SALU
    {
        const int cc = t;
        const short* myrow = &shPool[cc * 68];
        float accum = 0.f;
        int cur = __builtin_amdgcn_readfirstlane(sr[0]);
        for (int eb = 0; eb < ME; eb += 4) {
            short4 v4 = *(const short4*)&myrow[eb];
            short vj[4] = {v4.x, v4.y, v4.z, v4.w};
#pragma unroll
            for (int j = 0; j < 4; ++j) {
                float v = bf2f(vj[j]);
                int r = __builtin_amdgcn_readfirstlane(sr[eb + j]);
                if (r != cur) {
                    atomicAdd(&agg[(size_t)cur * HID + cc], accum);
                    accum = v;
                    cur = r;
                } else {
                    accum += v;
                }
            }
        }
        atomicAdd(&agg[(size_t)cur * HID + cc], accum);
    }
}

// ---------------- node MLP (bf16 MFMA), 64 nodes/block, biases via MFMA tails ----------------
// B-fragment loads amortized over 64 output rows (2x vs the 32-node version);
// LDS 52 KB -> 3 blocks/CU (throughput-bound kernel family; occupancy secondary).
__global__ __launch_bounds__(256, 3) void node_kernel(
    const short* __restrict__ hbf, const float* __restrict__ agg,
    const short* __restrict__ Wbn1, const short* __restrict__ Wbn2,
    float* __restrict__ out)
{
    __shared__ __align__(16) short pool[NB * 384];  // 48 KB: shH + shAg; shM overlays
    __shared__ __align__(16) short shTn[NB * 32];   // 4 KB bias K-tail {1,0,..}
    short* shH  = pool;                 // [64][128] bf16 (swizzled)
    short* shAg = pool + NB * 128;      // [64][256] bf16 (swizzled)
    short* shM  = pool;                 // [64][256] bf16 (swizzled) — overlays

    const int t  = threadIdx.x;
    const int n0 = blockIdx.x * NB;

    // ---- stage h (bf16 copy), agg (f32 -> bf16), bias tail; 4 threads/node ----
    {
        const int n = t >> 2, q = t & 3;
        int gn = n0 + n;
        if (gn >= N_NODES) gn = N_NODES - 1;   // clamp loads; stores guarded later
        const short8* hp = (const short8*)(hbf + (size_t)gn * HDIM + q * 32);
#pragma unroll
        for (int c = 0; c < 4; ++c) {
            short8 v = hp[c];
            int chunk = q * 4 + c;             // 0..15
            int sw = chunk ^ (n & 7);
            *(short8*)&shH[n * 128 + sw * 8] = v;
        }
        const float4* ap = (const float4*)(agg + (size_t)gn * HID + q * 64);
#pragma unroll
        for (int i = 0; i < 8; ++i) {
            float4 u0 = ap[2 * i], u1 = ap[2 * i + 1];
            short8 s;
            s[0] = f2bfn(u0.x); s[1] = f2bfn(u0.y); s[2] = f2bfn(u0.z); s[3] = f2bfn(u0.w);
            s[4] = f2bfn(u1.x); s[5] = f2bfn(u1.y); s[6] = f2bfn(u1.z); s[7] = f2bfn(u1.w);
            int chunk = q * 8 + i;             // 0..31
            int sw2 = chunk ^ (n & 7);
            *(short8*)&shAg[n * 256 + sw2 * 8] = s;
        }
        short8 z = {0, 0, 0, 0, 0, 0, 0, 0};
        if (q == 0) z[0] = (short)0x3F80;      // bf16 1.0
        *(short8*)&shTn[n * 32 + ((q ^ (n & 3)) << 3)] = z;
    }
    __syncthreads();

    const int l = t & 63, w = t >> 6;
    const int l15 = l & 15, lq = l >> 4;

    // ---- layer 1: K=384 (+32 bias tail), 256 cols, 64 rows ----
    f32x4 acc[4][4];
#pragma unroll
    for (int i = 0; i < 4; ++i)
#pragma unroll
        for (int j = 0; j < 4; ++j) acc[i][j] = (f32x4){0.f, 0.f, 0.f, 0.f};
#pragma unroll
    for (int ks = 0; ks < 12; ++ks) {
        short8 a[4], b[4];
#pragma unroll
        for (int et = 0; et < 4; ++et) {
            int r = et * 16 + l15;
            if (ks < 4) {
                int chunk = ks * 4 + lq;
                a[et] = *(const short8*)&shH[r * 128 + ((chunk ^ (r & 7)) << 3)];
            } else {
                int chunk = (ks - 4) * 4 + lq;
                a[et] = *(const short8*)&shAg[r * 256 + ((chunk ^ (r & 7)) << 3)];
            }
        }
#pragma unroll
        for (int ct = 0; ct < 4; ++ct) {
            int cc = w * 64 + ct * 16 + l15;
            b[ct] = *(const short8*)&Wbn1[cc * 416 + ks * 32 + lq * 8];
        }
#pragma unroll
        for (int et = 0; et < 4; ++et)
#pragma unroll
            for (int ct = 0; ct < 4; ++ct)
                acc[et][ct] = __builtin_amdgcn_mfma_f32_16x16x32_bf16(
                    a[et], b[ct], acc[et][ct], 0, 0, 0);
    }
    {   // bias tail (k = 384..415)
        short8 a[4], b[4];
#pragma unroll
        for (int et = 0; et < 4; ++et) {
            int r = et * 16 + l15;
            a[et] = *(const short8*)&shTn[r * 32 + ((lq ^ (r & 3)) << 3)];
        }
#pragma unroll
        for (int ct = 0; ct < 4; ++ct) {
            int cc = w * 64 + ct * 16 + l15;
            b[ct] = *(const short8*)&Wbn1[cc * 416 + 384 + lq * 8];
        }
#pragma unroll
        for (int et = 0; et < 4; ++et)
#pragma unroll
            for (int ct = 0; ct < 4; ++ct)
                acc[et][ct] = __builtin_amdgcn_mfma_f32_16x16x32_bf16(
                    a[et], b[ct], acc[et][ct], 0, 0, 0);
    }
    __syncthreads();   // done reading shH/shAg before shM overlay write

    // ---- SiLU -> M (bf16, swizzled; no bias add) ----
    {
#pragma unroll
        for (int et = 0; et < 4; ++et) {
#pragma unroll
            for (int rp = 0; rp < 2; ++rp) {
                int er0 = et * 16 + lq * 4 + rp * 2;
#pragma unroll
                for (int ct = 0; ct < 4; ++ct) {
                    int kc = w * 64 + ct * 16 + l15;
                    float y0 = silu(acc[et][ct][rp * 2]);
                    float y1 = silu(acc[et][ct][rp * 2 + 1]);
                    int khi = kc >> 3, klo = kc & 7;
                    shM[er0 * 256 + ((khi ^ (er0 & 7)) << 3) + klo] = f2bfn(y0);
                    shM[(er0 + 1) * 256 + ((khi ^ ((er0 + 1) & 7)) << 3) + klo] = f2bfn(y1);
                }
            }
        }
    }
    __syncthreads();

    // ---- layer 2: K=256 (+32 bias tail), 128 cols (32 per wave), 64 rows ----
    f32x4 acc2[4][2];
#pragma unroll
    for (int i = 0; i < 4; ++i)
#pragma unroll
        for (int j = 0; j < 2; ++j) acc2[i][j] = (f32x4){0.f, 0.f, 0.f, 0.f};
#pragma unroll
    for (int ks = 0; ks < 8; ++ks) {
        short8 a[4], b2[2];
#pragma unroll
        for (int et = 0; et < 4; ++et) {
            int r = et * 16 + l15;
            int chunk = ks * 4 + lq;
            a[et] = *(const short8*)&shM[r * 256 + ((chunk ^ (r & 7)) << 3)];
        }
#pragma unroll
        for (int ct = 0; ct < 2; ++ct) {
            int cc = w * 32 + ct * 16 + l15;
            b2[ct] = *(const short8*)&Wbn2[cc * 288 + ks * 32 + lq * 8];
        }
#pragma unroll
        for (int et = 0; et < 4; ++et)
#pragma unroll
            for (int ct = 0; ct < 2; ++ct)
                acc2[et][ct] = __builtin_amdgcn_mfma_f32_16x16x32_bf16(
                    a[et], b2[ct], acc2[et][ct], 0, 0, 0);
    }
    {   // bias tail (k = 256..287); shTn not overlaid
        short8 a[4], b2[2];
#pragma unroll
        for (int et = 0; et < 4; ++et) {
            int r = et * 16 + l15;
            a[et] = *(const short8*)&shTn[r * 32 + ((lq ^ (r & 3)) << 3)];
        }
#pragma unroll
        for (int ct = 0; ct < 2; ++ct) {
            int cc = w * 32 + ct * 16 + l15;
            b2[ct] = *(const short8*)&Wbn2[cc * 288 + 256 + lq * 8];
        }
#pragma unroll
        for (int et = 0; et < 4; ++et)
#pragma unroll
            for (int ct = 0; ct < 2; ++ct)
                acc2[et][ct] = __builtin_amdgcn_mfma_f32_16x16x32_bf16(
                    a[et], b2[ct], acc2[et][ct], 0, 0, 0);
    }

    // ---- store (bias already in acc2) ----
#pragma unroll
    for (int et = 0; et < 4; ++et) {
#pragma unroll
        for (int ct = 0; ct < 2; ++ct) {
            int cc = w * 32 + ct * 16 + l15;
#pragma unroll
            for (int r4 = 0; r4 < 4; ++r4) {
                int gn = n0 + et * 16 + lq * 4 + r4;
                if (gn < N_NODES)
                    out[(size_t)gn * HDIM + cc] = acc2[et][ct][r4];
            }
        }
    }
}

extern "C" void kernel_launch(void* const* d_in, const int* in_sizes, int n_in,
                              void* d_out, int out_size, void* d_ws, size_t ws_size,
                              hipStream_t stream) {
    const float* h   = (const float*)d_in[0];
    const float* cd  = (const float*)d_in[1];
    const int*   row = (const int*)d_in[2];
    const int*   col = (const int*)d_in[3];
    const float* We1 = (const float*)d_in[4];
    const float* be1 = (const float*)d_in[5];
    const float* We2 = (const float*)d_in[6];
    const float* be2 = (const float*)d_in[7];
    const float* Wn1 = (const float*)d_in[8];
    const float* bn1 = (const float*)d_in[9];
    const float* Wn2 = (const float*)d_in[10];
    const float* bn2 = (const float*)d_in[11];
    float* out = (float*)d_out;

    // ---- workspace layout ----
    short* Wb1  = (short*)d_ws;                       // 256*288
    short* Wb2  = Wb1 + 256 * 288;                    // 256*288
    short* Wbn1 = Wb2 + 256 * 288;                    // 256*416
    short* Wbn2 = Wbn1 + 256 * 416;                   // 128*288
    short* hbf  = Wbn2 + 128 * 288;                   // 50000*128
    float* agg  = (float*)(hbf + (size_t)N_NODES * HDIM);  // 50000*256 f32
    int*   cnt    = (int*)(agg + (size_t)N_NODES * HID);   // 50000
    int*   cursor = cnt + N_NODES;                    // 50000 (also scan scratch)
    int*   eidx   = cursor + N_NODES;                 // 800000
    int*   tsum   = eidx + E_EDGES;                   // 256
    int*   toff   = tsum + 256;                       // 256

    // cnt must be zero before prep's fused hist
    hipMemsetAsync(cnt, 0, N_NODES * sizeof(int), stream);

    // fused prep: h cvt + agg zero + hist + weight cvts (one launch)
    prep_kernel<<<PREP_WN2, 256, 0, stream>>>(h, hbf, agg, row, cnt,
                                              We1, be1, Wb1, We2, be2, Wb2,
                                              Wn1, bn1, Wbn1, Wn2, bn2, Wbn2);

    // parallel CSR scan -> cursor
    scanA_kernel<<<NTILES, 256, 0, stream>>>(cnt, cursor, tsum);
    scanB_kernel<<<1, 256, 0, stream>>>(tsum, toff);
    scanC_kernel<<<NTILES, 256, 0, stream>>>(cnt, cursor, toff);
    fill_kernel<<<(E_EDGES + 255) / 256, 256, 0, stream>>>(row, cursor, eidx);

    // main
    edge_kernel<<<E_EDGES / ME, 256, 0, stream>>>(hbf, cd, row, col, eidx,
                                                  Wb1, Wb2, agg);
    node_kernel<<<(N_NODES + NB - 1) / NB, 256, 0, stream>>>(hbf, agg, Wbn1, Wbn2, out);
}